// Round 5
// baseline (149.980 us; speedup 1.0000x reference)
//
#include <hip/hip_runtime.h>

// Problem constants
#define B_    4
#define A_    66000
#define NA_   (B_ * A_)          // 264000 anchors
#define N_    30
#define T_    5
#define NLT   5
#define CSUM  277
#define CTOT  278                // 1 + 277 logits per anchor
#define ROWS  31                 // N+1 table rows per batch
#define NROWS (B_ * ROWS)        // 124
#define WPR   16                 // u32 words per bit-row (9 used, padded to 16)
#define NBW   (NROWS * WPR)      // 1984 words = 7936 B
#define NE    (NA_ * CTOT)       // 73,392,000 elements
#define NE8   (NE / 8)           // 9,174,000 8-packs (exact)

#define BLK       256
#define GRID_CLS  2048
#define GRID_REG  512

typedef float fx4 __attribute__((ext_vector_type(4)));

// ---------------- helpers ----------------

// focal elem, y as bit of w at sh, c25/c75 = mask*0.25 / mask*0.75:
//   s = y ? -x : x;  elem = coef * softplus(s) * sigmoid(s)^2
__device__ __forceinline__ float focal_q(float x, unsigned w, unsigned sh,
                                         float c25, float c75, float acc) {
    bool y    = (w >> sh) & 1u;
    float s   = y ? -x : x;
    float coef= y ? c25 : c75;
    float t   = __expf(-fabsf(s));                 // exp(-|s|)
    float sp  = fmaxf(s, 0.f) + __logf(1.f + t);   // softplus(s)
    float inv = __builtin_amdgcn_rcpf(1.f + t);
    float sig = (s >= 0.f) ? inv : t * inv;        // sigmoid(s)
    return fmaf(coef * sp, sig * sig, acc);
}

__device__ __forceinline__ float sl1(float d) {
    float ad = fabsf(d);
    return (ad < (1.f / 9.f)) ? 4.5f * ad * ad : ad - (1.f / 18.f);
}

__device__ __forceinline__ float block_reduce(float v, float* sdata) {
    #pragma unroll
    for (int off = 32; off > 0; off >>= 1) v += __shfl_down(v, off, 64);
    int lane = threadIdx.x & 63, wid = threadIdx.x >> 6;
    if (lane == 0) sdata[wid] = v;
    __syncthreads();
    int nw = blockDim.x >> 6;
    if (wid == 0) {
        v = (lane < nw) ? sdata[lane] : 0.f;
        #pragma unroll
        for (int off = 32; off > 0; off >>= 1) v += __shfl_down(v, off, 64);
    }
    return v;
}

// ---------------- kernels ----------------

// Bit-packed label table: 124 rows x 16 u32. Bit c of row (b*31+dumy) is the
// label y for logit column c (col 0 = pos bit, cols 1..277 = class table).
__global__ void build_bits(const int* __restrict__ gtl, unsigned* __restrict__ bits) {
    for (int i = threadIdx.x; i < NBW; i += blockDim.x) bits[i] = 0u;
    __syncthreads();
    int tid = threadIdx.x;
    if (tid < NROWS) {
        if ((tid % ROWS) > 0) atomicOr(&bits[tid * WPR], 1u);   // pos bit
    }
    if (tid < B_ * N_ * NLT) {
        int lt = tid % NLT;
        int bn = tid / NLT;
        int n  = bn % N_;
        int b  = bn / N_;
        const int nc_arr[NLT]  = {10, 23, 69, 163, 12};
        const int off_arr[NLT] = {0, 10, 33, 102, 265};
        int nc  = nc_arr[lt];
        int off = off_arr[lt] + 1;              // +1: col 0 is pos
        const int* g = gtl + (size_t)(((b * N_ + n) * NLT + lt)) * T_;
        int row = b * ROWS + (n + 1);
        bool valid = true;
        #pragma unroll
        for (int t = 0; t < T_; ++t) {
            int v = g[t];
            valid = valid && (v >= 0);
            if (valid) {
                int c = off + ((v < nc) ? v : (nc - 1));
                atomicOr(&bits[row * WPR + (c >> 5)], 1u << (c & 31));
            }
        }
    }
}

// Regression loss + pos count + per-anchor rowid (word offset into bits,
// -1 = masked-out anchor).
__global__ __launch_bounds__(BLK) void reg_rowid_kernel(
    const float* __restrict__ pred, const float* __restrict__ gt,
    const int* __restrict__ lbin, int* __restrict__ rowid,
    float* __restrict__ reg_part, float* __restrict__ pos_part)
{
    float racc = 0.f, pacc = 0.f;
    unsigned stride = gridDim.x * blockDim.x;
    for (unsigned i = blockIdx.x * blockDim.x + threadIdx.x; i < NA_; i += stride) {
        int lb = lbin[i];
        unsigned b = i / A_;
        rowid[i] = (lb < 0) ? -1 : (int)((b * ROWS + (unsigned)(lb > 0 ? lb : 0)) * WPR);
        if (lb > 0) {
            pacc += 1.f;
            float4 pv = *(const float4*)(pred + (size_t)4 * i);
            float4 gv = *(const float4*)(gt + (size_t)4 * i);
            racc += sl1(pv.x - gv.x) + sl1(pv.y - gv.y) + sl1(pv.z - gv.z) + sl1(pv.w - gv.w);
        }
    }
    __shared__ float sdata[BLK / 64];
    float r = block_reduce(racc, sdata);
    __syncthreads();
    float p = block_reduce(pacc, sdata);
    if (threadIdx.x == 0) {
        reg_part[blockIdx.x] = r;
        pos_part[blockIdx.x] = p;
    }
}

// Main classification focal-loss sum: 32 B (8 elements) per lane-iteration.
// One rowid load, one div, one 64-bit bit-window per 8 elements.
__global__ __launch_bounds__(BLK) void cls_kernel(
    const fx4* __restrict__ conf4, const int* __restrict__ rowid,
    const unsigned* __restrict__ bits, float* __restrict__ partials)
{
    __shared__ unsigned lbits[NBW];
    for (int i = threadIdx.x; i < NBW; i += BLK) lbits[i] = bits[i];
    __syncthreads();

    float acc = 0.f;
    unsigned stride = gridDim.x * BLK;
    for (unsigned i = blockIdx.x * BLK + threadIdx.x; i < NE8; i += stride) {
        fx4 x0 = conf4[2u * i];          // elements 8i .. 8i+3
        fx4 x1 = conf4[2u * i + 1u];     // elements 8i+4 .. 8i+7
        unsigned i8 = i * 8u;
        unsigned a  = i8 / CTOT;         // magic-mul div
        unsigned c0 = i8 - a * CTOT;     // even, 0..270 fast / 272,274,276 slow
        int rid = rowid[a];

        if (c0 <= 270u) {
            // all 8 elements in anchor a; bits c0..c0+7 from 2 table words
            unsigned bw = (rid >= 0) ? (unsigned)rid : 0u;
            unsigned wi = c0 >> 5;                       // <= 8, WPR=16 pads
            unsigned w0 = lbits[bw + wi];
            unsigned w1 = lbits[bw + wi + 1u];
            unsigned long long ww = ((unsigned long long)w1 << 32) | (unsigned long long)w0;
            unsigned b8 = (unsigned)(ww >> (c0 & 31u));  // bits 0..7 = y for 8 elems
            float m = (rid >= 0) ? 1.f : 0.f;
            float c25 = 0.25f * m, c75 = 0.75f * m;
            acc = focal_q(x0.x, b8, 0u, c25, c75, acc);
            acc = focal_q(x0.y, b8, 1u, c25, c75, acc);
            acc = focal_q(x0.z, b8, 2u, c25, c75, acc);
            acc = focal_q(x0.w, b8, 3u, c25, c75, acc);
            acc = focal_q(x1.x, b8, 4u, c25, c75, acc);
            acc = focal_q(x1.y, b8, 5u, c25, c75, acc);
            acc = focal_q(x1.z, b8, 6u, c25, c75, acc);
            acc = focal_q(x1.w, b8, 7u, c25, c75, acc);
        } else {
            // pack crosses into anchor a+1 (c0 in {272,274,276}); rare (~2% of lanes)
            int rid2 = rowid[a + 1u];
            unsigned boundary = CTOT - c0;   // elements k < boundary are in anchor a
            #pragma unroll
            for (unsigned k = 0; k < 8u; ++k) {
                bool ina  = (k < boundary);
                int  rr   = ina ? rid : rid2;
                unsigned cc = ina ? (c0 + k) : (k - boundary);
                unsigned bwv = (rr >= 0) ? (unsigned)rr : 0u;
                unsigned wv = lbits[bwv + (cc >> 5)];
                float mm = (rr >= 0) ? 1.f : 0.f;
                float xk = (k < 4u) ? x0[k] : x1[k - 4u];
                acc = focal_q(xk, wv, cc & 31u, 0.25f * mm, 0.75f * mm, acc);
            }
        }
    }

    __shared__ float sdata[BLK / 64];
    float r = block_reduce(acc, sdata);
    if (threadIdx.x == 0) partials[blockIdx.x] = r;
}

// Deterministic final reduction + normalization.
__global__ void finalize_kernel(
    const float* __restrict__ cls_part, const float* __restrict__ reg_part,
    const float* __restrict__ pos_part, float* __restrict__ out)
{
    __shared__ float sdata[256 / 64];
    float c = 0.f, r = 0.f, pz = 0.f;
    for (int i = threadIdx.x; i < GRID_CLS; i += blockDim.x) c += cls_part[i];
    for (int i = threadIdx.x; i < GRID_REG; i += blockDim.x) {
        r  += reg_part[i];
        pz += pos_part[i];
    }
    c = block_reduce(c, sdata);
    __syncthreads();
    r = block_reduce(r, sdata);
    __syncthreads();
    pz = block_reduce(pz, sdata);
    if (threadIdx.x == 0) {
        float np = fmaxf(1.f, pz);
        out[0] = r / (np * 4.f);   // regression_loss
        out[1] = c / np;           // cls_loss
    }
}

// ---------------- launch ----------------

extern "C" void kernel_launch(void* const* d_in, const int* in_sizes, int n_in,
                              void* d_out, int out_size, void* d_ws, size_t ws_size,
                              hipStream_t stream) {
    const float* conf = (const float*)d_in[0];
    const float* pred = (const float*)d_in[1];
    const float* gt   = (const float*)d_in[2];
    const int*   gtl  = (const int*)d_in[3];
    const int*   lbin = (const int*)d_in[4];
    float* out = (float*)d_out;

    unsigned* bits  = (unsigned*)d_ws;
    int* rowid      = (int*)(bits + NBW);
    float* cls_part = (float*)(rowid + NA_);
    float* reg_part = cls_part + GRID_CLS;
    float* pos_part = reg_part + GRID_REG;

    hipLaunchKernelGGL(build_bits, dim3(1), dim3(1024), 0, stream, gtl, bits);
    hipLaunchKernelGGL(reg_rowid_kernel, dim3(GRID_REG), dim3(BLK), 0, stream,
                       pred, gt, lbin, rowid, reg_part, pos_part);
    hipLaunchKernelGGL(cls_kernel, dim3(GRID_CLS), dim3(BLK), 0, stream,
                       (const fx4*)conf, rowid, bits, cls_part);
    hipLaunchKernelGGL(finalize_kernel, dim3(1), dim3(256), 0, stream,
                       cls_part, reg_part, pos_part, out);
}

// Round 6
// 112.372 us; speedup vs baseline: 1.3347x; 1.3347x over previous
//
#include <hip/hip_runtime.h>

// Problem constants
#define B_    4
#define A_    66000
#define NA_   (B_ * A_)          // 264000 anchors
#define N_    30
#define T_    5
#define NLT   5
#define CSUM  277
#define CTOT  278                // 1 + 277 logits per anchor
#define ROWS  31                 // N+1 table rows per batch
#define NROWS (B_ * ROWS)        // 124
#define WPR   16                 // u32 words per bit-row (9 used, padded to 16)
#define NBW   (NROWS * WPR)      // 1984 words = 7936 B
#define NE    (NA_ * CTOT)       // 73,392,000 elements
#define NQ    (NE / 4)           // 18,348,000 float4 quads (exact)

#define BLK       256
#define GRID_CLS  2048
#define GRID_REG  512
#define STRIDE2   (GRID_CLS * BLK * 2u)   // quads consumed per unroll-2 outer iter
#define FULLIT2   (NQ / STRIDE2)          // 17 full iterations (17*1048576 = 17,825,792)

typedef float fx4 __attribute__((ext_vector_type(4)));

// ---------------- helpers ----------------

// focal elem, y as bit sh of w, c25/c75 = mask*0.25 / mask*0.75:
//   s = y ? -x : x;  elem = coef * softplus(s) * sigmoid(s)^2
__device__ __forceinline__ float focal_q(float x, unsigned w, unsigned sh,
                                         float c25, float c75, float acc) {
    bool y    = (w >> sh) & 1u;
    float s   = y ? -x : x;
    float coef= y ? c25 : c75;
    float t   = __expf(-fabsf(s));                 // exp(-|s|)
    float sp  = fmaxf(s, 0.f) + __logf(1.f + t);   // softplus(s)
    float inv = __builtin_amdgcn_rcpf(1.f + t);
    float sig = (s >= 0.f) ? inv : t * inv;        // sigmoid(s)
    return fmaf(coef * sp, sig * sig, acc);
}

__device__ __forceinline__ float sl1(float d) {
    float ad = fabsf(d);
    return (ad < (1.f / 9.f)) ? 4.5f * ad * ad : ad - (1.f / 18.f);
}

__device__ __forceinline__ float block_reduce(float v, float* sdata) {
    #pragma unroll
    for (int off = 32; off > 0; off >>= 1) v += __shfl_down(v, off, 64);
    int lane = threadIdx.x & 63, wid = threadIdx.x >> 6;
    if (lane == 0) sdata[wid] = v;
    __syncthreads();
    int nw = blockDim.x >> 6;
    if (wid == 0) {
        v = (lane < nw) ? sdata[lane] : 0.f;
        #pragma unroll
        for (int off = 32; off > 0; off >>= 1) v += __shfl_down(v, off, 64);
    }
    return v;
}

// one float4 quad: fast path uses a single 64-bit funnel-shift bit window.
__device__ __forceinline__ float do_quad(fx4 xv, unsigned a, unsigned c0, int rid,
                                         const int* __restrict__ rowid,
                                         const unsigned* lbits, float acc) {
    if (c0 != 276u) {
        unsigned bw = (rid >= 0) ? (unsigned)rid : 0u;
        unsigned wi = c0 >> 5;
        unsigned w0 = lbits[bw + wi];
        unsigned w1 = lbits[bw + wi + 1u];          // WPR=16 pad keeps this in-row
        unsigned long long ww = ((unsigned long long)w1 << 32) | (unsigned long long)w0;
        unsigned b4 = (unsigned)(ww >> (c0 & 31u)); // bits 0..3 = labels
        float m = (rid >= 0) ? 1.f : 0.f;
        float c25 = 0.25f * m, c75 = 0.75f * m;
        acc = focal_q(xv.x, b4, 0u, c25, c75, acc);
        acc = focal_q(xv.y, b4, 1u, c25, c75, acc);
        acc = focal_q(xv.z, b4, 2u, c25, c75, acc);
        acc = focal_q(xv.w, b4, 3u, c25, c75, acc);
    } else {  // elems 276,277 of anchor a; 0,1 of anchor a+1 (symmetric light body)
        int rid2 = rowid[a + 1u];
        unsigned wA = lbits[((rid  >= 0) ? (unsigned)rid  : 0u) + 8u];
        unsigned wB = lbits[ (rid2 >= 0) ? (unsigned)rid2 : 0u];
        float mA = (rid >= 0) ? 1.f : 0.f, mB = (rid2 >= 0) ? 1.f : 0.f;
        acc = focal_q(xv.x, wA, 20u, 0.25f * mA, 0.75f * mA, acc);
        acc = focal_q(xv.y, wA, 21u, 0.25f * mA, 0.75f * mA, acc);
        acc = focal_q(xv.z, wB, 0u, 0.25f * mB, 0.75f * mB, acc);
        acc = focal_q(xv.w, wB, 1u, 0.25f * mB, 0.75f * mB, acc);
    }
    return acc;
}

// ---------------- kernels ----------------

// Bit-packed label table: 124 rows x 16 u32. Bit c of row (b*31+dumy) is the
// label y for logit column c (col 0 = pos bit, cols 1..277 = class table).
__global__ void build_bits(const int* __restrict__ gtl, unsigned* __restrict__ bits) {
    for (int i = threadIdx.x; i < NBW; i += blockDim.x) bits[i] = 0u;
    __syncthreads();
    int tid = threadIdx.x;
    if (tid < NROWS) {
        if ((tid % ROWS) > 0) atomicOr(&bits[tid * WPR], 1u);   // pos bit
    }
    if (tid < B_ * N_ * NLT) {
        int lt = tid % NLT;
        int bn = tid / NLT;
        int n  = bn % N_;
        int b  = bn / N_;
        const int nc_arr[NLT]  = {10, 23, 69, 163, 12};
        const int off_arr[NLT] = {0, 10, 33, 102, 265};
        int nc  = nc_arr[lt];
        int off = off_arr[lt] + 1;              // +1: col 0 is pos
        const int* g = gtl + (size_t)(((b * N_ + n) * NLT + lt)) * T_;
        int row = b * ROWS + (n + 1);
        bool valid = true;
        #pragma unroll
        for (int t = 0; t < T_; ++t) {
            int v = g[t];
            valid = valid && (v >= 0);
            if (valid) {
                int c = off + ((v < nc) ? v : (nc - 1));
                atomicOr(&bits[row * WPR + (c >> 5)], 1u << (c & 31));
            }
        }
    }
}

// Regression loss + pos count + per-anchor rowid (word offset into bits,
// -1 = masked-out anchor).
__global__ __launch_bounds__(BLK) void reg_rowid_kernel(
    const float* __restrict__ pred, const float* __restrict__ gt,
    const int* __restrict__ lbin, int* __restrict__ rowid,
    float* __restrict__ reg_part, float* __restrict__ pos_part)
{
    float racc = 0.f, pacc = 0.f;
    unsigned stride = gridDim.x * blockDim.x;
    for (unsigned i = blockIdx.x * blockDim.x + threadIdx.x; i < NA_; i += stride) {
        int lb = lbin[i];
        unsigned b = i / A_;
        rowid[i] = (lb < 0) ? -1 : (int)((b * ROWS + (unsigned)(lb > 0 ? lb : 0)) * WPR);
        if (lb > 0) {
            pacc += 1.f;
            float4 pv = *(const float4*)(pred + (size_t)4 * i);
            float4 gv = *(const float4*)(gt + (size_t)4 * i);
            racc += sl1(pv.x - gv.x) + sl1(pv.y - gv.y) + sl1(pv.z - gv.z) + sl1(pv.w - gv.w);
        }
    }
    __shared__ float sdata[BLK / 64];
    float r = block_reduce(racc, sdata);
    __syncthreads();
    float p = block_reduce(pacc, sdata);
    if (threadIdx.x == 0) {
        reg_part[blockIdx.x] = r;
        pos_part[blockIdx.x] = p;
    }
}

// Main classification focal-loss sum: unroll-2, both loads issued before
// either quad's compute (MLP=2), high-occupancy launch bound.
__global__ __launch_bounds__(BLK, 8) void cls_kernel(
    const fx4* __restrict__ conf4, const int* __restrict__ rowid,
    const unsigned* __restrict__ bits, float* __restrict__ partials)
{
    __shared__ unsigned lbits[NBW];
    for (int i = threadIdx.x; i < NBW; i += BLK) lbits[i] = bits[i];
    __syncthreads();

    float acc = 0.f;
    unsigned base = blockIdx.x * (BLK * 2u) + threadIdx.x;

    for (unsigned it = 0; it < FULLIT2; ++it, base += STRIDE2) {
        unsigned iA = base, iB = base + BLK;
        fx4 xvA = conf4[iA];                 // two independent 16B streams
        fx4 xvB = conf4[iB];
        unsigned i4A = iA * 4u, i4B = iB * 4u;
        unsigned aA = i4A / CTOT, aB = i4B / CTOT;
        unsigned cA = i4A - aA * CTOT, cB = i4B - aB * CTOT;
        int rA = rowid[aA], rB = rowid[aB];
        acc = do_quad(xvA, aA, cA, rA, rowid, lbits, acc);
        acc = do_quad(xvB, aB, cB, rB, rowid, lbits, acc);
    }
    // tail
    #pragma unroll
    for (unsigned k = 0; k < 2; ++k) {
        unsigned i = base + k * BLK;
        if (i < NQ) {
            fx4 xv = conf4[i];
            unsigned i4 = i * 4u;
            unsigned a = i4 / CTOT;
            unsigned c0 = i4 - a * CTOT;
            acc = do_quad(xv, a, c0, rowid[a], rowid, lbits, acc);
        }
    }

    __shared__ float sdata[BLK / 64];
    float r = block_reduce(acc, sdata);
    if (threadIdx.x == 0) partials[blockIdx.x] = r;
}

// Deterministic final reduction + normalization.
__global__ void finalize_kernel(
    const float* __restrict__ cls_part, const float* __restrict__ reg_part,
    const float* __restrict__ pos_part, float* __restrict__ out)
{
    __shared__ float sdata[256 / 64];
    float c = 0.f, r = 0.f, pz = 0.f;
    for (int i = threadIdx.x; i < GRID_CLS; i += blockDim.x) c += cls_part[i];
    for (int i = threadIdx.x; i < GRID_REG; i += blockDim.x) {
        r  += reg_part[i];
        pz += pos_part[i];
    }
    c = block_reduce(c, sdata);
    __syncthreads();
    r = block_reduce(r, sdata);
    __syncthreads();
    pz = block_reduce(pz, sdata);
    if (threadIdx.x == 0) {
        float np = fmaxf(1.f, pz);
        out[0] = r / (np * 4.f);   // regression_loss
        out[1] = c / np;           // cls_loss
    }
}

// ---------------- launch ----------------

extern "C" void kernel_launch(void* const* d_in, const int* in_sizes, int n_in,
                              void* d_out, int out_size, void* d_ws, size_t ws_size,
                              hipStream_t stream) {
    const float* conf = (const float*)d_in[0];
    const float* pred = (const float*)d_in[1];
    const float* gt   = (const float*)d_in[2];
    const int*   gtl  = (const int*)d_in[3];
    const int*   lbin = (const int*)d_in[4];
    float* out = (float*)d_out;

    unsigned* bits  = (unsigned*)d_ws;
    int* rowid      = (int*)(bits + NBW);
    float* cls_part = (float*)(rowid + NA_);
    float* reg_part = cls_part + GRID_CLS;
    float* pos_part = reg_part + GRID_REG;

    hipLaunchKernelGGL(build_bits, dim3(1), dim3(1024), 0, stream, gtl, bits);
    hipLaunchKernelGGL(reg_rowid_kernel, dim3(GRID_REG), dim3(BLK), 0, stream,
                       pred, gt, lbin, rowid, reg_part, pos_part);
    hipLaunchKernelGGL(cls_kernel, dim3(GRID_CLS), dim3(BLK), 0, stream,
                       (const fx4*)conf, rowid, bits, cls_part);
    hipLaunchKernelGGL(finalize_kernel, dim3(1), dim3(256), 0, stream,
                       cls_part, reg_part, pos_part, out);
}

// Round 7
// 86.061 us; speedup vs baseline: 1.7427x; 1.3057x over previous
//
#include <hip/hip_runtime.h>

// Problem constants
#define B_    4
#define A_    66000
#define NA_   (B_ * A_)          // 264000 anchors
#define N_    30
#define T_    5
#define NLT   5
#define CSUM  277
#define CTOT  278                // 1 + 277 logits per anchor
#define ROWS  31                 // N+1 table rows per batch
#define NROWS (B_ * ROWS)        // 124
#define WPR   16                 // u32 words per bit-row (9 used, padded to 16)
#define NBW   (NROWS * WPR)      // 1984 words = 7936 B
#define NE    (NA_ * CTOT)       // 73,392,000 elements
#define NQ    (NE / 4)           // 18,348,000 float4 quads (exact)

#define BLK       256
#define GRID_CLS  2048
#define GRID_PREP 512

typedef float fx4 __attribute__((ext_vector_type(4)));
typedef float fx2 __attribute__((ext_vector_type(2)));

// ---------------- helpers ----------------

// Pair focal: elements share nothing but are evaluated as float2 math so the
// compiler can emit v_pk_*_f32 (double-rate packed f32 on CDNA4).
// b2 = 2 label bits; c25/c75 = mask*0.25 / mask*0.75 for this pair.
__device__ __forceinline__ fx2 pair_focal(float x0, float x1, unsigned b2,
                                          float c25, float c75, fx2 acc) {
    bool y0 = (b2 & 1u) != 0u, y1 = (b2 & 2u) != 0u;
    float s0 = y0 ? -x0 : x0,  s1 = y1 ? -x1 : x1;
    float k0 = y0 ? c25 : c75, k1 = y1 ? c25 : c75;
    // t = exp(-|s|) = exp2(-|x|*log2e)   (|s| == |x|)
    float t0 = __builtin_amdgcn_exp2f(-fabsf(x0) * 1.4426950408889634f);
    float t1 = __builtin_amdgcn_exp2f(-fabsf(x1) * 1.4426950408889634f);
    fx2 t = {t0, t1};
    fx2 u = t + 1.0f;
    fx2 L = { __builtin_amdgcn_logf(u.x), __builtin_amdgcn_logf(u.y) }; // log2(1+t)
    fx2 sp = { fmaxf(s0, 0.f), fmaxf(s1, 0.f) };
    sp += L * 0.6931471805599453f;                 // softplus(s)
    fx2 inv = { __builtin_amdgcn_rcpf(u.x), __builtin_amdgcn_rcpf(u.y) };
    fx2 ti = t * inv;
    fx2 sig = { s0 >= 0.f ? inv.x : ti.x, s1 >= 0.f ? inv.y : ti.y };   // sigmoid(s)
    fx2 term = { k0, k1 };
    term *= sp;
    return acc + term * (sig * sig);
}

__device__ __forceinline__ float sl1(float d) {
    float ad = fabsf(d);
    return (ad < (1.f / 9.f)) ? 4.5f * ad * ad : ad - (1.f / 18.f);
}

__device__ __forceinline__ float block_reduce(float v, float* sdata) {
    #pragma unroll
    for (int off = 32; off > 0; off >>= 1) v += __shfl_down(v, off, 64);
    int lane = threadIdx.x & 63, wid = threadIdx.x >> 6;
    if (lane == 0) sdata[wid] = v;
    __syncthreads();
    int nw = blockDim.x >> 6;
    if (wid == 0) {
        v = (lane < nw) ? sdata[lane] : 0.f;
        #pragma unroll
        for (int off = 32; off > 0; off >>= 1) v += __shfl_down(v, off, 64);
    }
    return v;
}

// ---------------- kernels ----------------

// Fused prep: block 0 builds the bit-packed label table; all blocks do the
// regression loss + pos count + per-anchor rowid.
__global__ __launch_bounds__(BLK) void prep_kernel(
    const int* __restrict__ gtl, const int* __restrict__ lbin,
    const float* __restrict__ pred, const float* __restrict__ gt,
    unsigned* __restrict__ bits, int* __restrict__ rowid,
    float* __restrict__ reg_part, float* __restrict__ pos_part)
{
    if (blockIdx.x == 0) {
        for (int i = threadIdx.x; i < NBW; i += BLK) bits[i] = 0u;
        __syncthreads();
        int tid = threadIdx.x;
        if (tid < NROWS && (tid % ROWS) > 0) atomicOr(&bits[tid * WPR], 1u); // pos bit
        for (int idx = tid; idx < B_ * N_ * NLT; idx += BLK) {
            int lt = idx % NLT;
            int bn = idx / NLT;
            int n  = bn % N_;
            int b  = bn / N_;
            const int nc_arr[NLT]  = {10, 23, 69, 163, 12};
            const int off_arr[NLT] = {0, 10, 33, 102, 265};
            int nc  = nc_arr[lt];
            int off = off_arr[lt] + 1;          // +1: col 0 is pos
            const int* g = gtl + (size_t)(((b * N_ + n) * NLT + lt)) * T_;
            int row = b * ROWS + (n + 1);
            bool valid = true;
            #pragma unroll
            for (int t = 0; t < T_; ++t) {
                int v = g[t];
                valid = valid && (v >= 0);
                if (valid) {
                    int c = off + ((v < nc) ? v : (nc - 1));
                    atomicOr(&bits[row * WPR + (c >> 5)], 1u << (c & 31));
                }
            }
        }
        if (tid == 0) rowid[NA_] = 0;           // sentinel for always-load rid2
    }

    float racc = 0.f, pacc = 0.f;
    unsigned stride = gridDim.x * BLK;
    for (unsigned i = blockIdx.x * BLK + threadIdx.x; i < NA_; i += stride) {
        int lb = lbin[i];
        unsigned b = i / A_;
        rowid[i] = (lb < 0) ? -1 : (int)((b * ROWS + (unsigned)(lb > 0 ? lb : 0)) * WPR);
        if (lb > 0) {
            pacc += 1.f;
            float4 pv = *(const float4*)(pred + (size_t)4 * i);
            float4 gv = *(const float4*)(gt + (size_t)4 * i);
            racc += sl1(pv.x - gv.x) + sl1(pv.y - gv.y) + sl1(pv.z - gv.z) + sl1(pv.w - gv.w);
        }
    }
    __shared__ float sdata[BLK / 64];
    float r = block_reduce(racc, sdata);
    __syncthreads();
    float p = block_reduce(pacc, sdata);
    if (threadIdx.x == 0) {
        reg_part[blockIdx.x] = r;
        pos_part[blockIdx.x] = p;
    }
}

// Main classification focal-loss sum: float4 grid-stride, fully branch-free
// boundary handling (no dual-body divergent execution).
__global__ __launch_bounds__(BLK) void cls_kernel(
    const fx4* __restrict__ conf4, const int* __restrict__ rowid,
    const unsigned* __restrict__ bits, float* __restrict__ partials)
{
    __shared__ unsigned lbits[NBW];
    for (int i = threadIdx.x; i < NBW; i += BLK) lbits[i] = bits[i];
    __syncthreads();

    fx2 acc2 = {0.f, 0.f};
    unsigned stride = gridDim.x * BLK;
    for (unsigned i = blockIdx.x * BLK + threadIdx.x; i < NQ; i += stride) {
        fx4 xv = conf4[i];
        unsigned i4 = i * 4u;
        unsigned a  = i4 / CTOT;          // magic-mul div
        unsigned c0 = i4 - a * CTOT;      // even, 0..276
        int ridA = rowid[a];
        int ridB = rowid[a + 1u];         // sentinel makes this always safe
        unsigned bwA = (ridA >= 0) ? (unsigned)ridA : 0u;
        unsigned bwB = (ridB >= 0) ? (unsigned)ridB : 0u;
        float mA = (ridA >= 0) ? 1.f : 0.f;
        float mB = (ridB >= 0) ? 1.f : 0.f;
        unsigned wi = c0 >> 5, sh = c0 & 31u;
        unsigned w0  = lbits[bwA + wi];
        unsigned w1  = lbits[bwA + wi + 1u];   // WPR=16 pad keeps in-row
        unsigned wB0 = lbits[bwB];
        // fast window: bits c0..c0+3 of row A (valid when c0 <= 274)
        unsigned wfast = (unsigned)((((unsigned long long)w1 << 32) | w0) >> sh);
        // slow window (c0==276): bits 276,277 of row A | bits 0,1 of row B
        unsigned wslow = ((w0 >> 20) & 3u) | ((wB0 & 3u) << 2);
        bool cross = (c0 == 276u);
        unsigned w4 = cross ? wslow : wfast;
        float m23 = cross ? mB : mA;
        acc2 = pair_focal(xv.x, xv.y, w4 & 3u,        0.25f * mA,  0.75f * mA,  acc2);
        acc2 = pair_focal(xv.z, xv.w, (w4 >> 2) & 3u, 0.25f * m23, 0.75f * m23, acc2);
    }

    __shared__ float sdata[BLK / 64];
    float r = block_reduce(acc2.x + acc2.y, sdata);
    if (threadIdx.x == 0) partials[blockIdx.x] = r;
}

// Deterministic final reduction + normalization.
__global__ void finalize_kernel(
    const float* __restrict__ cls_part, const float* __restrict__ reg_part,
    const float* __restrict__ pos_part, float* __restrict__ out)
{
    __shared__ float sdata[256 / 64];
    float c = 0.f, r = 0.f, pz = 0.f;
    for (int i = threadIdx.x; i < GRID_CLS; i += blockDim.x) c += cls_part[i];
    for (int i = threadIdx.x; i < GRID_PREP; i += blockDim.x) {
        r  += reg_part[i];
        pz += pos_part[i];
    }
    c = block_reduce(c, sdata);
    __syncthreads();
    r = block_reduce(r, sdata);
    __syncthreads();
    pz = block_reduce(pz, sdata);
    if (threadIdx.x == 0) {
        float np = fmaxf(1.f, pz);
        out[0] = r / (np * 4.f);   // regression_loss
        out[1] = c / np;           // cls_loss
    }
}

// ---------------- launch ----------------

extern "C" void kernel_launch(void* const* d_in, const int* in_sizes, int n_in,
                              void* d_out, int out_size, void* d_ws, size_t ws_size,
                              hipStream_t stream) {
    const float* conf = (const float*)d_in[0];
    const float* pred = (const float*)d_in[1];
    const float* gt   = (const float*)d_in[2];
    const int*   gtl  = (const int*)d_in[3];
    const int*   lbin = (const int*)d_in[4];
    float* out = (float*)d_out;

    unsigned* bits  = (unsigned*)d_ws;
    int* rowid      = (int*)(bits + NBW);          // NA_+1 entries (sentinel)
    float* cls_part = (float*)(rowid + NA_ + 1);
    float* reg_part = cls_part + GRID_CLS;
    float* pos_part = reg_part + GRID_PREP;

    hipLaunchKernelGGL(prep_kernel, dim3(GRID_PREP), dim3(BLK), 0, stream,
                       gtl, lbin, pred, gt, bits, rowid, reg_part, pos_part);
    hipLaunchKernelGGL(cls_kernel, dim3(GRID_CLS), dim3(BLK), 0, stream,
                       (const fx4*)conf, rowid, bits, cls_part);
    hipLaunchKernelGGL(finalize_kernel, dim3(1), dim3(256), 0, stream,
                       cls_part, reg_part, pos_part, out);
}

// Round 8
// 85.774 us; speedup vs baseline: 1.7485x; 1.0033x over previous
//
#include <hip/hip_runtime.h>

// Problem constants
#define B_    4
#define A_    66000
#define NA_   (B_ * A_)          // 264000 anchors
#define N_    30
#define T_    5
#define NLT   5
#define CSUM  277
#define CTOT  278                // 1 + 277 logits per anchor
#define ROWS  31                 // N+1 table rows per batch
#define NROWS (B_ * ROWS)        // 124
// WPR=11: odd stride, coprime with 32 banks. With WPR=16, row bases were
// multiples of 16 words -> all 64 lanes hit 2 banks (32-way conflict) on
// every table read. 11 spreads row bases over all 32 banks (~2-way, free).
// Needs >= 10 words so the unconditional w1=lbits[wi+1] read (wi<=8) stays in-row.
#define WPR   11
#define NBW   (NROWS * WPR)      // 1364 words = 5456 B
#define NE    (NA_ * CTOT)       // 73,392,000 elements
#define NQ    (NE / 4)           // 18,348,000 float4 quads (exact)

#define BLK       256
#define GRID_CLS  2048
#define GRID_PREP 512

typedef float fx4 __attribute__((ext_vector_type(4)));
typedef float fx2 __attribute__((ext_vector_type(2)));

// ---------------- helpers ----------------

// Pair focal: evaluated as float2 math so the compiler can emit v_pk_*_f32.
// b2 = 2 label bits; c25/c75 = mask*0.25 / mask*0.75 for this pair.
__device__ __forceinline__ fx2 pair_focal(float x0, float x1, unsigned b2,
                                          float c25, float c75, fx2 acc) {
    bool y0 = (b2 & 1u) != 0u, y1 = (b2 & 2u) != 0u;
    float s0 = y0 ? -x0 : x0,  s1 = y1 ? -x1 : x1;
    float k0 = y0 ? c25 : c75, k1 = y1 ? c25 : c75;
    // t = exp(-|s|) = exp2(-|x|*log2e)   (|s| == |x|)
    float t0 = __builtin_amdgcn_exp2f(-fabsf(x0) * 1.4426950408889634f);
    float t1 = __builtin_amdgcn_exp2f(-fabsf(x1) * 1.4426950408889634f);
    fx2 t = {t0, t1};
    fx2 u = t + 1.0f;
    fx2 L = { __builtin_amdgcn_logf(u.x), __builtin_amdgcn_logf(u.y) }; // log2(1+t)
    fx2 sp = { fmaxf(s0, 0.f), fmaxf(s1, 0.f) };
    sp += L * 0.6931471805599453f;                 // softplus(s)
    fx2 inv = { __builtin_amdgcn_rcpf(u.x), __builtin_amdgcn_rcpf(u.y) };
    fx2 ti = t * inv;
    fx2 sig = { s0 >= 0.f ? inv.x : ti.x, s1 >= 0.f ? inv.y : ti.y };   // sigmoid(s)
    fx2 term = { k0, k1 };
    term *= sp;
    return acc + term * (sig * sig);
}

__device__ __forceinline__ float sl1(float d) {
    float ad = fabsf(d);
    return (ad < (1.f / 9.f)) ? 4.5f * ad * ad : ad - (1.f / 18.f);
}

__device__ __forceinline__ float block_reduce(float v, float* sdata) {
    #pragma unroll
    for (int off = 32; off > 0; off >>= 1) v += __shfl_down(v, off, 64);
    int lane = threadIdx.x & 63, wid = threadIdx.x >> 6;
    if (lane == 0) sdata[wid] = v;
    __syncthreads();
    int nw = blockDim.x >> 6;
    if (wid == 0) {
        v = (lane < nw) ? sdata[lane] : 0.f;
        #pragma unroll
        for (int off = 32; off > 0; off >>= 1) v += __shfl_down(v, off, 64);
    }
    return v;
}

// ---------------- kernels ----------------

// Fused prep: block 0 builds the bit-packed label table; all blocks do the
// regression loss + pos count + per-anchor rowid.
__global__ __launch_bounds__(BLK) void prep_kernel(
    const int* __restrict__ gtl, const int* __restrict__ lbin,
    const float* __restrict__ pred, const float* __restrict__ gt,
    unsigned* __restrict__ bits, int* __restrict__ rowid,
    float* __restrict__ reg_part, float* __restrict__ pos_part)
{
    if (blockIdx.x == 0) {
        for (int i = threadIdx.x; i < NBW; i += BLK) bits[i] = 0u;
        __syncthreads();
        int tid = threadIdx.x;
        if (tid < NROWS && (tid % ROWS) > 0) atomicOr(&bits[tid * WPR], 1u); // pos bit
        for (int idx = tid; idx < B_ * N_ * NLT; idx += BLK) {
            int lt = idx % NLT;
            int bn = idx / NLT;
            int n  = bn % N_;
            int b  = bn / N_;
            const int nc_arr[NLT]  = {10, 23, 69, 163, 12};
            const int off_arr[NLT] = {0, 10, 33, 102, 265};
            int nc  = nc_arr[lt];
            int off = off_arr[lt] + 1;          // +1: col 0 is pos
            const int* g = gtl + (size_t)(((b * N_ + n) * NLT + lt)) * T_;
            int row = b * ROWS + (n + 1);
            bool valid = true;
            #pragma unroll
            for (int t = 0; t < T_; ++t) {
                int v = g[t];
                valid = valid && (v >= 0);
                if (valid) {
                    int c = off + ((v < nc) ? v : (nc - 1));
                    atomicOr(&bits[row * WPR + (c >> 5)], 1u << (c & 31));
                }
            }
        }
        if (tid == 0) rowid[NA_] = 0;           // sentinel for always-load rid2
    }

    float racc = 0.f, pacc = 0.f;
    unsigned stride = gridDim.x * BLK;
    for (unsigned i = blockIdx.x * BLK + threadIdx.x; i < NA_; i += stride) {
        int lb = lbin[i];
        unsigned b = i / A_;
        rowid[i] = (lb < 0) ? -1 : (int)((b * ROWS + (unsigned)(lb > 0 ? lb : 0)) * WPR);
        if (lb > 0) {
            pacc += 1.f;
            float4 pv = *(const float4*)(pred + (size_t)4 * i);
            float4 gv = *(const float4*)(gt + (size_t)4 * i);
            racc += sl1(pv.x - gv.x) + sl1(pv.y - gv.y) + sl1(pv.z - gv.z) + sl1(pv.w - gv.w);
        }
    }
    __shared__ float sdata[BLK / 64];
    float r = block_reduce(racc, sdata);
    __syncthreads();
    float p = block_reduce(pacc, sdata);
    if (threadIdx.x == 0) {
        reg_part[blockIdx.x] = r;
        pos_part[blockIdx.x] = p;
    }
}

// Main classification focal-loss sum: float4 grid-stride, fully branch-free
// boundary handling (no dual-body divergent execution).
__global__ __launch_bounds__(BLK) void cls_kernel(
    const fx4* __restrict__ conf4, const int* __restrict__ rowid,
    const unsigned* __restrict__ bits, float* __restrict__ partials)
{
    __shared__ unsigned lbits[NBW];
    for (int i = threadIdx.x; i < NBW; i += BLK) lbits[i] = bits[i];
    __syncthreads();

    fx2 acc2 = {0.f, 0.f};
    unsigned stride = gridDim.x * BLK;
    for (unsigned i = blockIdx.x * BLK + threadIdx.x; i < NQ; i += stride) {
        fx4 xv = conf4[i];
        unsigned i4 = i * 4u;
        unsigned a  = i4 / CTOT;          // magic-mul div
        unsigned c0 = i4 - a * CTOT;      // even, 0..276
        int ridA = rowid[a];
        int ridB = rowid[a + 1u];         // sentinel makes this always safe
        unsigned bwA = (ridA >= 0) ? (unsigned)ridA : 0u;
        unsigned bwB = (ridB >= 0) ? (unsigned)ridB : 0u;
        float mA = (ridA >= 0) ? 1.f : 0.f;
        float mB = (ridB >= 0) ? 1.f : 0.f;
        unsigned wi = c0 >> 5, sh = c0 & 31u;
        unsigned w0  = lbits[bwA + wi];
        unsigned w1  = lbits[bwA + wi + 1u];   // WPR=11 >= 10 keeps this in-row
        unsigned wB0 = lbits[bwB];
        // fast window: bits c0..c0+3 of row A (valid when c0 <= 274)
        unsigned wfast = (unsigned)((((unsigned long long)w1 << 32) | w0) >> sh);
        // slow window (c0==276): bits 276,277 of row A | bits 0,1 of row B
        unsigned wslow = ((w0 >> 20) & 3u) | ((wB0 & 3u) << 2);
        bool cross = (c0 == 276u);
        unsigned w4 = cross ? wslow : wfast;
        float m23 = cross ? mB : mA;
        acc2 = pair_focal(xv.x, xv.y, w4 & 3u,        0.25f * mA,  0.75f * mA,  acc2);
        acc2 = pair_focal(xv.z, xv.w, (w4 >> 2) & 3u, 0.25f * m23, 0.75f * m23, acc2);
    }

    __shared__ float sdata[BLK / 64];
    float r = block_reduce(acc2.x + acc2.y, sdata);
    if (threadIdx.x == 0) partials[blockIdx.x] = r;
}

// Deterministic final reduction + normalization.
__global__ void finalize_kernel(
    const float* __restrict__ cls_part, const float* __restrict__ reg_part,
    const float* __restrict__ pos_part, float* __restrict__ out)
{
    __shared__ float sdata[256 / 64];
    float c = 0.f, r = 0.f, pz = 0.f;
    for (int i = threadIdx.x; i < GRID_CLS; i += blockDim.x) c += cls_part[i];
    for (int i = threadIdx.x; i < GRID_PREP; i += blockDim.x) {
        r  += reg_part[i];
        pz += pos_part[i];
    }
    c = block_reduce(c, sdata);
    __syncthreads();
    r = block_reduce(r, sdata);
    __syncthreads();
    pz = block_reduce(pz, sdata);
    if (threadIdx.x == 0) {
        float np = fmaxf(1.f, pz);
        out[0] = r / (np * 4.f);   // regression_loss
        out[1] = c / np;           // cls_loss
    }
}

// ---------------- launch ----------------

extern "C" void kernel_launch(void* const* d_in, const int* in_sizes, int n_in,
                              void* d_out, int out_size, void* d_ws, size_t ws_size,
                              hipStream_t stream) {
    const float* conf = (const float*)d_in[0];
    const float* pred = (const float*)d_in[1];
    const float* gt   = (const float*)d_in[2];
    const int*   gtl  = (const int*)d_in[3];
    const int*   lbin = (const int*)d_in[4];
    float* out = (float*)d_out;

    unsigned* bits  = (unsigned*)d_ws;
    int* rowid      = (int*)(bits + NBW);          // NA_+1 entries (sentinel)
    float* cls_part = (float*)(rowid + NA_ + 1);
    float* reg_part = cls_part + GRID_CLS;
    float* pos_part = reg_part + GRID_PREP;

    hipLaunchKernelGGL(prep_kernel, dim3(GRID_PREP), dim3(BLK), 0, stream,
                       gtl, lbin, pred, gt, bits, rowid, reg_part, pos_part);
    hipLaunchKernelGGL(cls_kernel, dim3(GRID_CLS), dim3(BLK), 0, stream,
                       (const fx4*)conf, rowid, bits, cls_part);
    hipLaunchKernelGGL(finalize_kernel, dim3(1), dim3(256), 0, stream,
                       cls_part, reg_part, pos_part, out);
}

// Round 9
// 76.673 us; speedup vs baseline: 1.9561x; 1.1187x over previous
//
#include <hip/hip_runtime.h>

// Problem constants
#define B_    4
#define A_    66000
#define NA_   (B_ * A_)          // 264000 anchors
#define N_    30
#define T_    5
#define NLT   5
#define CSUM  277
#define CTOT  278                // 1 + 277 logits per anchor
#define ROWS  31                 // N+1 table rows per batch
#define NROWS (B_ * ROWS)        // 124
#define WPR   11                 // odd row stride (bank-neutral, >=10 for w1 read)
#define NBW   (NROWS * WPR)      // 1364 words
#define NE    (NA_ * CTOT)       // 73,392,000 elements
#define NE8   (NE / 8)           // 9,174,000 8-packs (exact)

#define BLK       256
#define GRID_CLS  2048
#define GRID_PREP 512

typedef float fx4 __attribute__((ext_vector_type(4)));
typedef float fx2 __attribute__((ext_vector_type(2)));

// ---------------- helpers ----------------

// Pair focal as float2 math (invites v_pk_*_f32).
// b2 = 2 label bits; c25/c75 = mask*0.25 / mask*0.75 for this pair.
__device__ __forceinline__ fx2 pair_focal(float x0, float x1, unsigned b2,
                                          float c25, float c75, fx2 acc) {
    bool y0 = (b2 & 1u) != 0u, y1 = (b2 & 2u) != 0u;
    float s0 = y0 ? -x0 : x0,  s1 = y1 ? -x1 : x1;
    float k0 = y0 ? c25 : c75, k1 = y1 ? c25 : c75;
    // t = exp(-|s|) = exp2(-|x|*log2e)   (|s| == |x|)
    float t0 = __builtin_amdgcn_exp2f(-fabsf(x0) * 1.4426950408889634f);
    float t1 = __builtin_amdgcn_exp2f(-fabsf(x1) * 1.4426950408889634f);
    fx2 t = {t0, t1};
    fx2 u = t + 1.0f;
    fx2 L = { __builtin_amdgcn_logf(u.x), __builtin_amdgcn_logf(u.y) }; // log2(1+t)
    fx2 sp = { fmaxf(s0, 0.f), fmaxf(s1, 0.f) };
    sp += L * 0.6931471805599453f;                 // softplus(s)
    fx2 inv = { __builtin_amdgcn_rcpf(u.x), __builtin_amdgcn_rcpf(u.y) };
    fx2 ti = t * inv;
    fx2 sig = { s0 >= 0.f ? inv.x : ti.x, s1 >= 0.f ? inv.y : ti.y };   // sigmoid(s)
    fx2 term = { k0, k1 };
    term *= sp;
    return acc + term * (sig * sig);
}

__device__ __forceinline__ float sl1(float d) {
    float ad = fabsf(d);
    return (ad < (1.f / 9.f)) ? 4.5f * ad * ad : ad - (1.f / 18.f);
}

__device__ __forceinline__ float block_reduce(float v, float* sdata) {
    #pragma unroll
    for (int off = 32; off > 0; off >>= 1) v += __shfl_down(v, off, 64);
    int lane = threadIdx.x & 63, wid = threadIdx.x >> 6;
    if (lane == 0) sdata[wid] = v;
    __syncthreads();
    int nw = blockDim.x >> 6;
    if (wid == 0) {
        v = (lane < nw) ? sdata[lane] : 0.f;
        #pragma unroll
        for (int off = 32; off > 0; off >>= 1) v += __shfl_down(v, off, 64);
    }
    return v;
}

// ---------------- kernels ----------------

// Fused prep: block 0 builds the bit-packed label table; all blocks do the
// regression loss + pos count + per-anchor rowid.
__global__ __launch_bounds__(BLK) void prep_kernel(
    const int* __restrict__ gtl, const int* __restrict__ lbin,
    const float* __restrict__ pred, const float* __restrict__ gt,
    unsigned* __restrict__ bits, int* __restrict__ rowid,
    float* __restrict__ reg_part, float* __restrict__ pos_part)
{
    if (blockIdx.x == 0) {
        for (int i = threadIdx.x; i < NBW; i += BLK) bits[i] = 0u;
        __syncthreads();
        int tid = threadIdx.x;
        if (tid < NROWS && (tid % ROWS) > 0) atomicOr(&bits[tid * WPR], 1u); // pos bit
        for (int idx = tid; idx < B_ * N_ * NLT; idx += BLK) {
            int lt = idx % NLT;
            int bn = idx / NLT;
            int n  = bn % N_;
            int b  = bn / N_;
            const int nc_arr[NLT]  = {10, 23, 69, 163, 12};
            const int off_arr[NLT] = {0, 10, 33, 102, 265};
            int nc  = nc_arr[lt];
            int off = off_arr[lt] + 1;          // +1: col 0 is pos
            const int* g = gtl + (size_t)(((b * N_ + n) * NLT + lt)) * T_;
            int row = b * ROWS + (n + 1);
            bool valid = true;
            #pragma unroll
            for (int t = 0; t < T_; ++t) {
                int v = g[t];
                valid = valid && (v >= 0);
                if (valid) {
                    int c = off + ((v < nc) ? v : (nc - 1));
                    atomicOr(&bits[row * WPR + (c >> 5)], 1u << (c & 31));
                }
            }
        }
        if (tid == 0) rowid[NA_] = 0;           // sentinel for always-load rid2
    }

    float racc = 0.f, pacc = 0.f;
    unsigned stride = gridDim.x * BLK;
    for (unsigned i = blockIdx.x * BLK + threadIdx.x; i < NA_; i += stride) {
        int lb = lbin[i];
        unsigned b = i / A_;
        rowid[i] = (lb < 0) ? -1 : (int)((b * ROWS + (unsigned)(lb > 0 ? lb : 0)) * WPR);
        if (lb > 0) {
            pacc += 1.f;
            float4 pv = *(const float4*)(pred + (size_t)4 * i);
            float4 gv = *(const float4*)(gt + (size_t)4 * i);
            racc += sl1(pv.x - gv.x) + sl1(pv.y - gv.y) + sl1(pv.z - gv.z) + sl1(pv.w - gv.w);
        }
    }
    __shared__ float sdata[BLK / 64];
    float r = block_reduce(racc, sdata);
    __syncthreads();
    float p = block_reduce(pacc, sdata);
    if (threadIdx.x == 0) {
        reg_part[blockIdx.x] = r;
        pos_part[blockIdx.x] = p;
    }
}

// Main classification focal-loss sum: 32 B (8 elements) per lane-iteration,
// fully branch-free boundary handling (no dual-body divergent execution).
// Per 8 elements: 1 magic-div, 2 rowid loads, 3 LDS broadcasts, 1 window.
__global__ __launch_bounds__(BLK) void cls_kernel(
    const fx4* __restrict__ conf4, const int* __restrict__ rowid,
    const unsigned* __restrict__ bits, float* __restrict__ partials)
{
    __shared__ unsigned lbits[NBW];
    for (int i = threadIdx.x; i < NBW; i += BLK) lbits[i] = bits[i];
    __syncthreads();

    fx2 acc2 = {0.f, 0.f};
    unsigned stride = gridDim.x * BLK;
    for (unsigned i = blockIdx.x * BLK + threadIdx.x; i < NE8; i += stride) {
        fx4 x0 = conf4[2u * i];          // elements 8i..8i+3
        fx4 x1 = conf4[2u * i + 1u];     // elements 8i+4..8i+7
        unsigned i8 = i * 8u;
        unsigned a  = i8 / CTOT;         // magic-mul div
        unsigned c0 = i8 - a * CTOT;     // even, 0..276
        int ridA = rowid[a];
        int ridB = rowid[a + 1u];        // sentinel makes this always safe
        unsigned bwA = (ridA >= 0) ? (unsigned)ridA : 0u;
        unsigned bwB = (ridB >= 0) ? (unsigned)ridB : 0u;
        float mA = (ridA >= 0) ? 1.f : 0.f;
        float mB = (ridB >= 0) ? 1.f : 0.f;
        unsigned wi = c0 >> 5, sh = c0 & 31u;     // wi <= 8
        unsigned w0  = lbits[bwA + wi];
        unsigned w1  = lbits[bwA + wi + 1u];      // WPR=11 keeps this in-row
        unsigned wB0 = lbits[bwB];
        // 8-bit window of row-A labels at c0 (sh+7 <= 38 < 64: always covered)
        unsigned wfull = (unsigned)((((unsigned long long)w1 << 32) | w0) >> sh);
        unsigned bnd  = CTOT - c0;                // elements k < bnd belong to A
        bool cross    = bnd < 8u;                 // c0 in {272,274,276}
        unsigned bndc = cross ? bnd : 8u;
        unsigned w8   = cross ? ((wfull & ((1u << bndc) - 1u)) | (wB0 << bndc))
                              : wfull;
        // bnd is even -> pairs never straddle the boundary
        float m1 = (cross && bnd <= 2u) ? mB : mA;   // elems 2,3
        float m2 = (cross && bnd <= 4u) ? mB : mA;   // elems 4,5
        float m3 = cross               ? mB : mA;    // elems 6,7 (bnd<=6 always)
        acc2 = pair_focal(x0.x, x0.y,  w8 & 3u,       0.25f * mA, 0.75f * mA, acc2);
        acc2 = pair_focal(x0.z, x0.w, (w8 >> 2) & 3u, 0.25f * m1, 0.75f * m1, acc2);
        acc2 = pair_focal(x1.x, x1.y, (w8 >> 4) & 3u, 0.25f * m2, 0.75f * m2, acc2);
        acc2 = pair_focal(x1.z, x1.w, (w8 >> 6) & 3u, 0.25f * m3, 0.75f * m3, acc2);
    }

    __shared__ float sdata[BLK / 64];
    float r = block_reduce(acc2.x + acc2.y, sdata);
    if (threadIdx.x == 0) partials[blockIdx.x] = r;
}

// Deterministic final reduction + normalization.
__global__ void finalize_kernel(
    const float* __restrict__ cls_part, const float* __restrict__ reg_part,
    const float* __restrict__ pos_part, float* __restrict__ out)
{
    __shared__ float sdata[256 / 64];
    float c = 0.f, r = 0.f, pz = 0.f;
    for (int i = threadIdx.x; i < GRID_CLS; i += blockDim.x) c += cls_part[i];
    for (int i = threadIdx.x; i < GRID_PREP; i += blockDim.x) {
        r  += reg_part[i];
        pz += pos_part[i];
    }
    c = block_reduce(c, sdata);
    __syncthreads();
    r = block_reduce(r, sdata);
    __syncthreads();
    pz = block_reduce(pz, sdata);
    if (threadIdx.x == 0) {
        float np = fmaxf(1.f, pz);
        out[0] = r / (np * 4.f);   // regression_loss
        out[1] = c / np;           // cls_loss
    }
}

// ---------------- launch ----------------

extern "C" void kernel_launch(void* const* d_in, const int* in_sizes, int n_in,
                              void* d_out, int out_size, void* d_ws, size_t ws_size,
                              hipStream_t stream) {
    const float* conf = (const float*)d_in[0];
    const float* pred = (const float*)d_in[1];
    const float* gt   = (const float*)d_in[2];
    const int*   gtl  = (const int*)d_in[3];
    const int*   lbin = (const int*)d_in[4];
    float* out = (float*)d_out;

    unsigned* bits  = (unsigned*)d_ws;
    int* rowid      = (int*)(bits + NBW);          // NA_+1 entries (sentinel)
    float* cls_part = (float*)(rowid + NA_ + 1);
    float* reg_part = cls_part + GRID_CLS;
    float* pos_part = reg_part + GRID_PREP;

    hipLaunchKernelGGL(prep_kernel, dim3(GRID_PREP), dim3(BLK), 0, stream,
                       gtl, lbin, pred, gt, bits, rowid, reg_part, pos_part);
    hipLaunchKernelGGL(cls_kernel, dim3(GRID_CLS), dim3(BLK), 0, stream,
                       (const fx4*)conf, rowid, bits, cls_part);
    hipLaunchKernelGGL(finalize_kernel, dim3(1), dim3(256), 0, stream,
                       cls_part, reg_part, pos_part, out);
}